// Round 1
// baseline (5280.522 us; speedup 1.0000x reference)
//
#include <hip/hip_runtime.h>
#include <math.h>

// Problem constants
#define BB    2
#define NSEQ  2048
#define DDIM  1024
#define HHE   16
#define HDIM  64
#define EEXP  8
#define FDIM  4096
#define TDIM  (BB*NSEQ)     // 4096 tokens

// ---------------- RMSNorm: one block per row (1024 floats, 256 thr x float4) ---------
__global__ __launch_bounds__(256) void rmsnorm_kernel(const float* __restrict__ x,
                                                      const float* __restrict__ w,
                                                      float* __restrict__ y) {
    int row = blockIdx.x;
    const float4* xr = (const float4*)(x + (size_t)row * DDIM);
    float4 v = xr[threadIdx.x];
    float ss = v.x*v.x + v.y*v.y + v.z*v.z + v.w*v.w;
    #pragma unroll
    for (int m = 1; m < 64; m <<= 1) ss += __shfl_xor(ss, m);
    __shared__ float wsum[4];
    int wid = threadIdx.x >> 6;
    if ((threadIdx.x & 63) == 0) wsum[wid] = ss;
    __syncthreads();
    float tot = wsum[0] + wsum[1] + wsum[2] + wsum[3];
    float inv = 1.0f / sqrtf(tot * (1.0f / DDIM) + 1e-6f);
    float4 wv = ((const float4*)w)[threadIdx.x];
    float4 o;
    o.x = v.x * inv * wv.x; o.y = v.y * inv * wv.y;
    o.z = v.z * inv * wv.z; o.w = v.w * inv * wv.w;
    ((float4*)(y + (size_t)row * DDIM))[threadIdx.x] = o;
}

// ---------------- Generic fp32 GEMM: Y[M,N] = X[M,K] @ W[N,K]^T -----------------------
// 64x64 tile, BK=32, 256 threads, 4x4 acc per thread. Optional gathered X rows
// (expert lists) and epilogues.
#define BM 64
#define BN 64
#define BKK 32

enum { EP_PLAIN = 0, EP_SIGMOID = 1, EP_RESID = 2, EP_SILU = 3, EP_SCATTER = 4 };

__device__ __forceinline__ float sigmoidf_(float x) { return 1.0f / (1.0f + __expf(-x)); }

template <int MODE, bool GATHER>
__global__ __launch_bounds__(256) void gemm_kernel(
    const float* __restrict__ X, const float* __restrict__ W, float* __restrict__ Y,
    int M, int Nout, int Kdim,
    const int* __restrict__ ridx, const float* __restrict__ rwgt,
    const int* __restrict__ cntp,
    const float* __restrict__ add1, const float* __restrict__ mul1) {
    int Mact = cntp ? *cntp : M;
    int rowTile = blockIdx.y;
    if (rowTile * BM >= Mact) return;
    int colTile = blockIdx.x;

    __shared__ float Xs[BKK][BM + 4];
    __shared__ float Wsh[BKK][BN + 4];

    int tid = threadIdx.x;
    int lm = tid >> 3;      // 0..31
    int kq = tid & 7;       // 0..7 -> k-offset kq*4

    int gm0 = rowTile * BM + lm;
    int gm1 = gm0 + 32;
    const float* xr0;
    const float* xr1;
    if (GATHER) {
        int safe = ridx[rowTile * BM];                 // rowTile*BM < Mact guaranteed
        int t0 = (gm0 < Mact) ? ridx[gm0] : safe;
        int t1 = (gm1 < Mact) ? ridx[gm1] : safe;
        xr0 = X + (size_t)t0 * Kdim;
        xr1 = X + (size_t)t1 * Kdim;
    } else {
        xr0 = X + (size_t)gm0 * Kdim;
        xr1 = X + (size_t)gm1 * Kdim;
    }
    const float* wr0 = W + (size_t)(colTile * BN + lm) * Kdim;
    const float* wr1 = wr0 + (size_t)32 * Kdim;

    int tn = tid & 15;      // 0..15 -> cols tn*4..+3
    int tm = tid >> 4;      // 0..15 -> rows tm*4..+3
    float acc[4][4] = {};

    for (int k0 = 0; k0 < Kdim; k0 += BKK) {
        float4 a0 = *(const float4*)(xr0 + k0 + kq * 4);
        float4 a1 = *(const float4*)(xr1 + k0 + kq * 4);
        float4 b0 = *(const float4*)(wr0 + k0 + kq * 4);
        float4 b1 = *(const float4*)(wr1 + k0 + kq * 4);
        __syncthreads();   // previous iteration's reads done
        Xs[kq*4+0][lm] = a0.x; Xs[kq*4+1][lm] = a0.y; Xs[kq*4+2][lm] = a0.z; Xs[kq*4+3][lm] = a0.w;
        Xs[kq*4+0][lm+32] = a1.x; Xs[kq*4+1][lm+32] = a1.y; Xs[kq*4+2][lm+32] = a1.z; Xs[kq*4+3][lm+32] = a1.w;
        Wsh[kq*4+0][lm] = b0.x; Wsh[kq*4+1][lm] = b0.y; Wsh[kq*4+2][lm] = b0.z; Wsh[kq*4+3][lm] = b0.w;
        Wsh[kq*4+0][lm+32] = b1.x; Wsh[kq*4+1][lm+32] = b1.y; Wsh[kq*4+2][lm+32] = b1.z; Wsh[kq*4+3][lm+32] = b1.w;
        __syncthreads();
        #pragma unroll
        for (int kk = 0; kk < BKK; ++kk) {
            float4 a4 = *(const float4*)&Xs[kk][tm * 4];
            float4 b4 = *(const float4*)&Wsh[kk][tn * 4];
            float av[4] = {a4.x, a4.y, a4.z, a4.w};
            float bv[4] = {b4.x, b4.y, b4.z, b4.w};
            #pragma unroll
            for (int i = 0; i < 4; ++i)
                #pragma unroll
                for (int j = 0; j < 4; ++j)
                    acc[i][j] = fmaf(av[i], bv[j], acc[i][j]);
        }
    }

    #pragma unroll
    for (int i = 0; i < 4; ++i) {
        int gm = rowTile * BM + tm * 4 + i;
        int gn = colTile * BN + tn * 4;
        if constexpr (MODE == EP_SILU || MODE == EP_SCATTER) {
            if (gm >= Mact) continue;
        }
        if constexpr (MODE == EP_PLAIN) {
            float4 o = {acc[i][0], acc[i][1], acc[i][2], acc[i][3]};
            *(float4*)(Y + (size_t)gm * Nout + gn) = o;
        } else if constexpr (MODE == EP_SIGMOID) {
            float4 o = {sigmoidf_(acc[i][0]), sigmoidf_(acc[i][1]),
                        sigmoidf_(acc[i][2]), sigmoidf_(acc[i][3])};
            *(float4*)(Y + (size_t)gm * Nout + gn) = o;
        } else if constexpr (MODE == EP_RESID) {
            size_t off = (size_t)gm * Nout + gn;
            float4 xa = *(const float4*)(add1 + off);
            float4 ga = *(const float4*)(mul1 + off);
            float4 o;
            o.x = xa.x + acc[i][0] * ga.x; o.y = xa.y + acc[i][1] * ga.y;
            o.z = xa.z + acc[i][2] * ga.z; o.w = xa.w + acc[i][3] * ga.w;
            *(float4*)(Y + off) = o;
        } else if constexpr (MODE == EP_SILU) {
            float4 o;
            o.x = acc[i][0] * sigmoidf_(acc[i][0]);
            o.y = acc[i][1] * sigmoidf_(acc[i][1]);
            o.z = acc[i][2] * sigmoidf_(acc[i][2]);
            o.w = acc[i][3] * sigmoidf_(acc[i][3]);
            *(float4*)(Y + (size_t)gm * Nout + gn) = o;
        } else {  // EP_SCATTER: Y[token] += acc * coef
            int tok = ridx[gm];
            float cw = rwgt[gm];
            float* yr = Y + (size_t)tok * Nout + gn;
            atomicAdd(yr + 0, acc[i][0] * cw);
            atomicAdd(yr + 1, acc[i][1] * cw);
            atomicAdd(yr + 2, acc[i][2] * cw);
            atomicAdd(yr + 3, acc[i][3] * cw);
        }
    }
}

// ---------------- Flash-style attention, fp32 -----------------------------------------
// grid (N/64, B*H), block 256. Thread (r=tid/4, c=tid%3bits): row r, quarter c.
__global__ __launch_bounds__(256) void attn_kernel(const float* __restrict__ q,
                                                   const float* __restrict__ k,
                                                   const float* __restrict__ v,
                                                   float* __restrict__ o) {
    __shared__ float4 Ks[64 * 16];
    __shared__ float4 Vs[64 * 16];
    int bh = blockIdx.y;
    int b = bh >> 4, h = bh & 15;
    int r = threadIdx.x >> 2, c = threadIdx.x & 3;
    int n0 = blockIdx.x * 64 + r;

    const float4* qr = (const float4*)(q + ((size_t)(b * NSEQ + n0)) * DDIM + h * HDIM);
    float4 qv[16];
    #pragma unroll
    for (int i = 0; i < 16; ++i) qv[i] = qr[i];

    float4 oacc[4];
    #pragma unroll
    for (int i = 0; i < 4; ++i) oacc[i] = make_float4(0.f, 0.f, 0.f, 0.f);
    float mrun = -INFINITY, lrun = 0.f;

    int jr = threadIdx.x >> 4;   // 0..15
    int d4 = threadIdx.x & 15;   // 0..15

    for (int kt = 0; kt < NSEQ / 64; ++kt) {
        #pragma unroll
        for (int rr = 0; rr < 4; ++rr) {
            int j = rr * 16 + jr;
            size_t base = ((size_t)(b * NSEQ + kt * 64 + j)) * DDIM + h * HDIM;
            Ks[j * 16 + d4] = *(const float4*)(k + base + d4 * 4);
            Vs[j * 16 + d4] = *(const float4*)(v + base + d4 * 4);
        }
        __syncthreads();

        float p[16];
        float tmax = -INFINITY;
        #pragma unroll
        for (int jj = 0; jj < 16; ++jj) {
            int j = c * 16 + jj;
            float4 sa = make_float4(0.f, 0.f, 0.f, 0.f);
            #pragma unroll
            for (int d = 0; d < 16; ++d) {
                float4 kv = Ks[j * 16 + d];
                sa.x = fmaf(qv[d].x, kv.x, sa.x);
                sa.y = fmaf(qv[d].y, kv.y, sa.y);
                sa.z = fmaf(qv[d].z, kv.z, sa.z);
                sa.w = fmaf(qv[d].w, kv.w, sa.w);
            }
            float s = (sa.x + sa.y + sa.z + sa.w) * 0.125f;  // 1/sqrt(64)
            p[jj] = s;
            tmax = fmaxf(tmax, s);
        }
        tmax = fmaxf(tmax, __shfl_xor(tmax, 1));
        tmax = fmaxf(tmax, __shfl_xor(tmax, 2));
        float mnew = fmaxf(mrun, tmax);
        float alpha = __expf(mrun - mnew);
        float tsum = 0.f;
        #pragma unroll
        for (int jj = 0; jj < 16; ++jj) { p[jj] = __expf(p[jj] - mnew); tsum += p[jj]; }
        tsum += __shfl_xor(tsum, 1);
        tsum += __shfl_xor(tsum, 2);
        lrun = lrun * alpha + tsum;
        mrun = mnew;
        #pragma unroll
        for (int t4 = 0; t4 < 4; ++t4) {
            oacc[t4].x *= alpha; oacc[t4].y *= alpha; oacc[t4].z *= alpha; oacc[t4].w *= alpha;
        }
        #pragma unroll
        for (int cc = 0; cc < 4; ++cc) {
            #pragma unroll
            for (int jj = 0; jj < 16; ++jj) {
                float pj = __shfl(p[jj], cc, 4);
                int j = cc * 16 + jj;
                #pragma unroll
                for (int t4 = 0; t4 < 4; ++t4) {
                    float4 vv = Vs[j * 16 + c * 4 + t4];
                    oacc[t4].x = fmaf(pj, vv.x, oacc[t4].x);
                    oacc[t4].y = fmaf(pj, vv.y, oacc[t4].y);
                    oacc[t4].z = fmaf(pj, vv.z, oacc[t4].z);
                    oacc[t4].w = fmaf(pj, vv.w, oacc[t4].w);
                }
            }
        }
        __syncthreads();
    }

    float invl = 1.0f / lrun;
    float* orow = o + ((size_t)(b * NSEQ + n0)) * DDIM + h * HDIM + c * 16;
    #pragma unroll
    for (int t4 = 0; t4 < 4; ++t4) {
        float4 ov;
        ov.x = oacc[t4].x * invl; ov.y = oacc[t4].y * invl;
        ov.z = oacc[t4].z * invl; ov.w = oacc[t4].w * invl;
        *(float4*)(orow + t4 * 4) = ov;
    }
}

// ---------------- MoE router ----------------------------------------------------------
__global__ __launch_bounds__(256) void moe_gate_kernel(const float* __restrict__ h2,
                                                       const float* __restrict__ wg,
                                                       float* __restrict__ logits) {
    int t = blockIdx.x * 32 + (threadIdx.x >> 3);
    int e = threadIdx.x & 7;
    const float4* xr = (const float4*)(h2 + (size_t)t * DDIM);
    const float4* wr = (const float4*)(wg + (size_t)e * DDIM);
    float s = 0.f;
    for (int d = 0; d < DDIM / 4; ++d) {
        float4 a = xr[d], b = wr[d];
        s = fmaf(a.x, b.x, s); s = fmaf(a.y, b.y, s);
        s = fmaf(a.z, b.z, s); s = fmaf(a.w, b.w, s);
    }
    logits[t * EEXP + e] = s;
}

__global__ void route_kernel(const float* __restrict__ logits, int* __restrict__ cnt,
                             int* __restrict__ idxl, float* __restrict__ wgtl) {
    int t = blockIdx.x * 256 + threadIdx.x;
    if (t >= TDIM) return;
    float l[EEXP];
    #pragma unroll
    for (int e = 0; e < EEXP; ++e) l[e] = logits[t * EEXP + e];
    int e0 = 0; float v0 = l[0];
    #pragma unroll
    for (int e = 1; e < EEXP; ++e) if (l[e] > v0) { v0 = l[e]; e0 = e; }
    int e1 = -1; float v1 = -INFINITY;
    #pragma unroll
    for (int e = 0; e < EEXP; ++e) if (e != e0 && l[e] > v1) { v1 = l[e]; e1 = e; }
    float r = __expf(v1 - v0);           // stable 2-way softmax, v0 is max
    float den = 1.0f + r;
    float w0 = 1.0f / den, w1 = r / den;
    int p0 = atomicAdd(&cnt[e0], 1);
    idxl[e0 * TDIM + p0] = t; wgtl[e0 * TDIM + p0] = w0;
    int p1 = atomicAdd(&cnt[e1], 1);
    idxl[e1 * TDIM + p1] = t; wgtl[e1 * TDIM + p1] = w1;
}

__global__ void zero_cnt_kernel(int* cnt) {
    if (threadIdx.x < EEXP) cnt[threadIdx.x] = 0;
}

// ---------------- launch --------------------------------------------------------------
extern "C" void kernel_launch(void* const* d_in, const int* in_sizes, int n_in,
                              void* d_out, int out_size, void* d_ws, size_t ws_size,
                              hipStream_t stream) {
    const float* x   = (const float*)d_in[0];
    const float* n1w = (const float*)d_in[1];
    const float* n2w = (const float*)d_in[2];
    const float* wq  = (const float*)d_in[3];
    const float* wk  = (const float*)d_in[4];
    const float* wv  = (const float*)d_in[5];
    const float* wo  = (const float*)d_in[6];
    const float* wg  = (const float*)d_in[7];
    const float* wmg = (const float*)d_in[8];
    const float* w1  = (const float*)d_in[9];
    const float* w2  = (const float*)d_in[10];
    float* out = (float*)d_out;

    float* ws = (float*)d_ws;
    const size_t TD = (size_t)TDIM * DDIM;      // 4M floats
    float* h1 = ws;                              // h1 then h2 (reuse)
    float* qb = ws + TD;
    float* kb = ws + 2 * TD;
    float* vb = ws + 3 * TD;
    float* gb = ws + 4 * TD;
    float* ab = ws + 5 * TD;
    float* Hbuf = qb;                            // 4096*4096 floats; reused after O-proj
    float* logits = ws + 6 * TD;
    float* wgtl = logits + (size_t)TDIM * EEXP;
    int* idxl = (int*)(wgtl + (size_t)TDIM * EEXP);
    int* cnt = (int*)(idxl + (size_t)TDIM * EEXP);

    zero_cnt_kernel<<<1, 64, 0, stream>>>(cnt);
    rmsnorm_kernel<<<TDIM, 256, 0, stream>>>(x, n1w, h1);

    dim3 gproj(DDIM / BN, TDIM / BM);   // (16,64)
    gemm_kernel<EP_PLAIN, false><<<gproj, 256, 0, stream>>>(h1, wq, qb, TDIM, DDIM, DDIM,
        nullptr, nullptr, nullptr, nullptr, nullptr);
    gemm_kernel<EP_PLAIN, false><<<gproj, 256, 0, stream>>>(h1, wk, kb, TDIM, DDIM, DDIM,
        nullptr, nullptr, nullptr, nullptr, nullptr);
    gemm_kernel<EP_PLAIN, false><<<gproj, 256, 0, stream>>>(h1, wv, vb, TDIM, DDIM, DDIM,
        nullptr, nullptr, nullptr, nullptr, nullptr);
    gemm_kernel<EP_SIGMOID, false><<<gproj, 256, 0, stream>>>(h1, wg, gb, TDIM, DDIM, DDIM,
        nullptr, nullptr, nullptr, nullptr, nullptr);

    attn_kernel<<<dim3(NSEQ / 64, BB * HHE), 256, 0, stream>>>(qb, kb, vb, ab);

    // out = x + (attn @ wo^T) * gate   (residual 1 lives in d_out)
    gemm_kernel<EP_RESID, false><<<gproj, 256, 0, stream>>>(ab, wo, out, TDIM, DDIM, DDIM,
        nullptr, nullptr, nullptr, x, gb);

    rmsnorm_kernel<<<TDIM, 256, 0, stream>>>(out, n2w, h1);   // h2 in h1 slot
    moe_gate_kernel<<<TDIM / 32, 256, 0, stream>>>(h1, wmg, logits);
    route_kernel<<<TDIM / 256, 256, 0, stream>>>(logits, cnt, idxl, wgtl);

    dim3 gup(FDIM / BN, TDIM / BM);   // (64,64)
    dim3 gdn(DDIM / BN, TDIM / BM);   // (16,64)
    for (int e = 0; e < EEXP; ++e) {
        gemm_kernel<EP_SILU, true><<<gup, 256, 0, stream>>>(h1, w1 + (size_t)e * FDIM * DDIM,
            Hbuf, TDIM, FDIM, DDIM, idxl + e * TDIM, nullptr, cnt + e, nullptr, nullptr);
        gemm_kernel<EP_SCATTER, false><<<gdn, 256, 0, stream>>>(Hbuf, w2 + (size_t)e * DDIM * FDIM,
            out, TDIM, DDIM, FDIM, idxl + e * TDIM, wgtl + e * TDIM, cnt + e, nullptr, nullptr);
    }
}

// Round 2
// 1702.543 us; speedup vs baseline: 3.1016x; 3.1016x over previous
//
#include <hip/hip_runtime.h>
#include <math.h>

#define BB    2
#define NSEQ  2048
#define DDIM  1024
#define HHE   16
#define HDIM  64
#define EEXP  8
#define FDIM  4096
#define TDIM  (BB*NSEQ)     // 4096 tokens

typedef unsigned short u16;
typedef __attribute__((ext_vector_type(8))) short bf16x8;
typedef __attribute__((ext_vector_type(4))) float f32x4;

__device__ __forceinline__ u16 f2bf(float f) {
    union { float f; unsigned u; } v; v.f = f;
    unsigned r = v.u + 0x7fffu + ((v.u >> 16) & 1u);   // RNE to bf16
    return (u16)(r >> 16);
}
__device__ __forceinline__ float sigmoidf_(float x) { return 1.0f / (1.0f + __expf(-x)); }

__device__ __forceinline__ void gl_lds16(const u16* g, u16* l) {
    __builtin_amdgcn_global_load_lds((const __attribute__((address_space(1))) unsigned*)g,
                                     (__attribute__((address_space(3))) unsigned*)l,
                                     16, 0, 0);
}

// ---------------- fp32 -> bf16 bulk convert ------------------------------------------
__global__ __launch_bounds__(256) void cvt_kernel(const float* __restrict__ in,
                                                  u16* __restrict__ out, int n4) {
    int i = blockIdx.x * 256 + threadIdx.x;
    int stride = gridDim.x * 256;
    for (; i < n4; i += stride) {
        float4 v = ((const float4*)in)[i];
        ushort4 o;
        o.x = f2bf(v.x); o.y = f2bf(v.y); o.z = f2bf(v.z); o.w = f2bf(v.w);
        ((ushort4*)out)[i] = o;
    }
}

// ---------------- RMSNorm: bf16 out (+ optional fp32 out) ----------------------------
template <bool WF32>
__global__ __launch_bounds__(256) void rmsnorm_kernel(const float* __restrict__ x,
                                                      const float* __restrict__ w,
                                                      u16* __restrict__ yb,
                                                      float* __restrict__ yf) {
    int row = blockIdx.x;
    const float4* xr = (const float4*)(x + (size_t)row * DDIM);
    float4 v = xr[threadIdx.x];
    float ss = v.x*v.x + v.y*v.y + v.z*v.z + v.w*v.w;
    #pragma unroll
    for (int m = 1; m < 64; m <<= 1) ss += __shfl_xor(ss, m);
    __shared__ float wsum[4];
    if ((threadIdx.x & 63) == 0) wsum[threadIdx.x >> 6] = ss;
    __syncthreads();
    float tot = wsum[0] + wsum[1] + wsum[2] + wsum[3];
    float inv = 1.0f / sqrtf(tot * (1.0f / DDIM) + 1e-6f);
    float4 wv = ((const float4*)w)[threadIdx.x];
    float4 o;
    o.x = v.x*inv*wv.x; o.y = v.y*inv*wv.y; o.z = v.z*inv*wv.z; o.w = v.w*inv*wv.w;
    ushort4 ob; ob.x = f2bf(o.x); ob.y = f2bf(o.y); ob.z = f2bf(o.z); ob.w = f2bf(o.w);
    ((ushort4*)(yb + (size_t)row * DDIM))[threadIdx.x] = ob;
    if constexpr (WF32)
        ((float4*)(yf + (size_t)row * DDIM))[threadIdx.x] = o;
}

// ---------------- bf16 MFMA GEMM (m97 structure): Y[M,N] = X[M,K] @ W[N,K]^T ---------
// 128x128 tile, BK=32, 256 thr = 4 waves (2x2), 4x4 16x16x32 frags/wave.
enum { EP_PLAIN = 0, EP_RESID = 2, EP_SILU = 3, EP_SCATTER = 4 };

template <int MODE, bool GATHER>
__global__ __launch_bounds__(256) void mgemm(
    const u16* __restrict__ X, const u16* __restrict__ Wb,
    float* __restrict__ Yf, u16* __restrict__ Yb,
    int Nout, int Kdim, int Mfull,
    const int* __restrict__ cnt, const int* __restrict__ offs,
    const int* __restrict__ idxl, const float* __restrict__ wgtl,
    const float* __restrict__ add1, const float* __restrict__ mul1, int mulStride) {
    int e = blockIdx.z;
    int Mact = cnt ? cnt[e] : Mfull;
    int rowTile = blockIdx.y;
    if (rowTile * 128 >= Mact) return;
    int colTile = blockIdx.x;
    const u16* W = Wb + (size_t)e * ((size_t)Nout * Kdim);
    const int* ridx = idxl ? idxl + e * TDIM : (const int*)nullptr;
    const float* rwgt = wgtl ? wgtl + e * TDIM : (const float*)nullptr;
    int rowBase = offs ? offs[e] : 0;

    __shared__ u16 As[128 * 32];
    __shared__ u16 Bs[128 * 32];

    int tid = threadIdx.x;
    const u16* aSrc[2]; const u16* bSrc[2];
    u16* aDst[2]; u16* bDst[2];
    #pragma unroll
    for (int i = 0; i < 2; ++i) {
        int f = i * 256 + tid;
        int r = f >> 2, kg = (f & 3) * 8;
        int gr = rowTile * 128 + r;
        size_t xrow;
        if constexpr (MODE == EP_SCATTER) xrow = (size_t)(rowBase + gr);
        else if constexpr (GATHER)        xrow = (size_t)ridx[gr < Mact ? gr : rowTile * 128];
        else                              xrow = (size_t)gr;
        aSrc[i] = X + xrow * Kdim + kg;
        bSrc[i] = W + (size_t)(colTile * 128 + r) * Kdim + kg;
        aDst[i] = &As[f * 8];
        bDst[i] = &Bs[f * 8];
    }

    int lane = tid & 63, wave = tid >> 6;
    int wr = wave >> 1, wc = wave & 1;
    int lr = lane & 15, lk = (lane >> 4) * 8;
    int aOff[4], bOff[4];
    #pragma unroll
    for (int i = 0; i < 4; ++i) {
        aOff[i] = (wr * 64 + i * 16 + lr) * 32 + lk;
        bOff[i] = (wc * 64 + i * 16 + lr) * 32 + lk;
    }
    f32x4 acc[4][4];
    #pragma unroll
    for (int mi = 0; mi < 4; ++mi)
        #pragma unroll
        for (int ni = 0; ni < 4; ++ni) {
            f32x4 z = {0.f, 0.f, 0.f, 0.f};
            acc[mi][ni] = z;
        }

    for (int k0 = 0; k0 < Kdim; k0 += 32) {
        __syncthreads();                 // prior tile's reads complete
        #pragma unroll
        for (int i = 0; i < 2; ++i) {
            gl_lds16(aSrc[i] + k0, aDst[i]);
            gl_lds16(bSrc[i] + k0, bDst[i]);
        }
        __syncthreads();                 // staging drained (vmcnt before barrier)
        bf16x8 af[4], bfr[4];
        #pragma unroll
        for (int i = 0; i < 4; ++i) af[i] = *(const bf16x8*)&As[aOff[i]];
        #pragma unroll
        for (int i = 0; i < 4; ++i) bfr[i] = *(const bf16x8*)&Bs[bOff[i]];
        #pragma unroll
        for (int mi = 0; mi < 4; ++mi)
            #pragma unroll
            for (int ni = 0; ni < 4; ++ni)
                acc[mi][ni] = __builtin_amdgcn_mfma_f32_16x16x32_bf16(
                    af[mi], bfr[ni], acc[mi][ni], 0, 0, 0);
    }

    int row0 = rowTile * 128 + wr * 64;
    int col0 = colTile * 128 + wc * 64;
    #pragma unroll
    for (int mi = 0; mi < 4; ++mi) {
        #pragma unroll
        for (int r = 0; r < 4; ++r) {
            int gm = row0 + mi * 16 + (lane >> 4) * 4 + r;
            bool mok = (MODE == EP_SILU || MODE == EP_SCATTER) ? (gm < Mact) : true;
            #pragma unroll
            for (int ni = 0; ni < 4; ++ni) {
                int gc = col0 + ni * 16 + lr;
                float val = acc[mi][ni][r];
                if constexpr (MODE == EP_PLAIN) {
                    Yf[(size_t)gm * Nout + gc] = val;
                } else if constexpr (MODE == EP_RESID) {
                    size_t off = (size_t)gm * Nout + gc;
                    Yf[off] = add1[off] + val * sigmoidf_(mul1[(size_t)gm * mulStride + gc]);
                } else if constexpr (MODE == EP_SILU) {
                    if (mok) Yb[(size_t)(rowBase + gm) * Nout + gc] = f2bf(val * sigmoidf_(val));
                } else {  // EP_SCATTER
                    if (mok) atomicAdd(&Yf[(size_t)ridx[gm] * Nout + gc], val * rwgt[gm]);
                }
            }
        }
    }
}

// ---------------- Flash attention fp32, K-tile XOR-swizzled, bf16 out ----------------
// qkvg: [T][4096] fp32, cols 0..1023=q, 1024..2047=k, 2048..3071=v.
__global__ __launch_bounds__(256) void attn_kernel(const float* __restrict__ qkvg,
                                                   u16* __restrict__ ob) {
    __shared__ float4 Ks[64 * 16];
    __shared__ float4 Vs[64 * 16];
    int b = blockIdx.y >> 4, h = blockIdx.y & 15;
    int r = threadIdx.x >> 2, c = threadIdx.x & 3;
    int n0 = blockIdx.x * 64 + r;

    const float* qrow = qkvg + (size_t)(b * NSEQ + n0) * 4096 + h * HDIM;
    float4 qv[16];
    #pragma unroll
    for (int i = 0; i < 16; ++i) qv[i] = ((const float4*)qrow)[i];

    float4 oacc[4];
    #pragma unroll
    for (int i = 0; i < 4; ++i) oacc[i] = make_float4(0.f, 0.f, 0.f, 0.f);
    float mrun = -INFINITY, lrun = 0.f;

    int jr = threadIdx.x >> 4;   // 0..15
    int d4 = threadIdx.x & 15;   // 0..15

    for (int kt = 0; kt < NSEQ / 64; ++kt) {
        #pragma unroll
        for (int rr = 0; rr < 4; ++rr) {
            int j = rr * 16 + jr;
            const float* kvrow = qkvg + (size_t)(b * NSEQ + kt * 64 + j) * 4096 + h * HDIM;
            Ks[j * 16 + (d4 ^ rr)] = *(const float4*)(kvrow + 1024 + d4 * 4);  // swizzled
            Vs[j * 16 + d4]        = *(const float4*)(kvrow + 2048 + d4 * 4);
        }
        __syncthreads();

        float p[16];
        float tmax = -INFINITY;
        #pragma unroll
        for (int jj = 0; jj < 16; ++jj) {
            int j = c * 16 + jj;
            float4 sa = make_float4(0.f, 0.f, 0.f, 0.f);
            #pragma unroll
            for (int d = 0; d < 16; ++d) {
                float4 kv = Ks[j * 16 + (d ^ c)];   // j>>4 == c
                sa.x = fmaf(qv[d].x, kv.x, sa.x);
                sa.y = fmaf(qv[d].y, kv.y, sa.y);
                sa.z = fmaf(qv[d].z, kv.z, sa.z);
                sa.w = fmaf(qv[d].w, kv.w, sa.w);
            }
            float s = (sa.x + sa.y + sa.z + sa.w) * 0.125f;
            p[jj] = s;
            tmax = fmaxf(tmax, s);
        }
        tmax = fmaxf(tmax, __shfl_xor(tmax, 1));
        tmax = fmaxf(tmax, __shfl_xor(tmax, 2));
        float mnew = fmaxf(mrun, tmax);
        float alpha = __expf(mrun - mnew);
        float tsum = 0.f;
        #pragma unroll
        for (int jj = 0; jj < 16; ++jj) { p[jj] = __expf(p[jj] - mnew); tsum += p[jj]; }
        tsum += __shfl_xor(tsum, 1);
        tsum += __shfl_xor(tsum, 2);
        lrun = lrun * alpha + tsum;
        mrun = mnew;
        #pragma unroll
        for (int t4 = 0; t4 < 4; ++t4) {
            oacc[t4].x *= alpha; oacc[t4].y *= alpha; oacc[t4].z *= alpha; oacc[t4].w *= alpha;
        }
        #pragma unroll
        for (int cc = 0; cc < 4; ++cc) {
            #pragma unroll
            for (int jj = 0; jj < 16; ++jj) {
                float pj = __shfl(p[jj], cc, 4);
                int j = cc * 16 + jj;
                #pragma unroll
                for (int t4 = 0; t4 < 4; ++t4) {
                    float4 vv = Vs[j * 16 + c * 4 + t4];
                    oacc[t4].x = fmaf(pj, vv.x, oacc[t4].x);
                    oacc[t4].y = fmaf(pj, vv.y, oacc[t4].y);
                    oacc[t4].z = fmaf(pj, vv.z, oacc[t4].z);
                    oacc[t4].w = fmaf(pj, vv.w, oacc[t4].w);
                }
            }
        }
        __syncthreads();
    }

    float invl = 1.0f / lrun;
    u16* orow = ob + (size_t)(b * NSEQ + n0) * DDIM + h * HDIM + c * 16;
    #pragma unroll
    for (int t4 = 0; t4 < 4; ++t4) {
        ushort4 o;
        o.x = f2bf(oacc[t4].x * invl); o.y = f2bf(oacc[t4].y * invl);
        o.z = f2bf(oacc[t4].z * invl); o.w = f2bf(oacc[t4].w * invl);
        *(ushort4*)(orow + t4 * 4) = o;
    }
}

// ---------------- MoE router (fp32 logits to avoid expert flips) ---------------------
__global__ __launch_bounds__(256) void moe_gate_kernel(const float* __restrict__ h2,
                                                       const float* __restrict__ wg,
                                                       float* __restrict__ logits) {
    int t = blockIdx.x * 32 + (threadIdx.x >> 3);
    int e = threadIdx.x & 7;
    const float4* xr = (const float4*)(h2 + (size_t)t * DDIM);
    const float4* wr = (const float4*)(wg + (size_t)e * DDIM);
    float s = 0.f;
    for (int d = 0; d < DDIM / 4; ++d) {
        float4 a = xr[d], b = wr[d];
        s = fmaf(a.x, b.x, s); s = fmaf(a.y, b.y, s);
        s = fmaf(a.z, b.z, s); s = fmaf(a.w, b.w, s);
    }
    logits[t * EEXP + e] = s;
}

__global__ void route_kernel(const float* __restrict__ logits, int* __restrict__ cnt,
                             int* __restrict__ idxl, float* __restrict__ wgtl) {
    int t = blockIdx.x * 256 + threadIdx.x;
    if (t >= TDIM) return;
    float l[EEXP];
    #pragma unroll
    for (int e = 0; e < EEXP; ++e) l[e] = logits[t * EEXP + e];
    int e0 = 0; float v0 = l[0];
    #pragma unroll
    for (int e = 1; e < EEXP; ++e) if (l[e] > v0) { v0 = l[e]; e0 = e; }
    int e1 = -1; float v1 = -INFINITY;
    #pragma unroll
    for (int e = 0; e < EEXP; ++e) if (e != e0 && l[e] > v1) { v1 = l[e]; e1 = e; }
    float rr = __expf(v1 - v0);
    float den = 1.0f + rr;
    float w0 = 1.0f / den, w1 = rr / den;
    int p0 = atomicAdd(&cnt[e0], 1);
    idxl[e0 * TDIM + p0] = t; wgtl[e0 * TDIM + p0] = w0;
    int p1 = atomicAdd(&cnt[e1], 1);
    idxl[e1 * TDIM + p1] = t; wgtl[e1 * TDIM + p1] = w1;
}

__global__ void prefix_kernel(const int* __restrict__ cnt, int* __restrict__ offs) {
    if (threadIdx.x == 0) {
        int s = 0;
        for (int e = 0; e < EEXP; ++e) { offs[e] = s; s += cnt[e]; }
    }
}

// ---------------- launch -------------------------------------------------------------
extern "C" void kernel_launch(void* const* d_in, const int* in_sizes, int n_in,
                              void* d_out, int out_size, void* d_ws, size_t ws_size,
                              hipStream_t stream) {
    const float* x   = (const float*)d_in[0];
    const float* n1w = (const float*)d_in[1];
    const float* n2w = (const float*)d_in[2];
    const float* wq  = (const float*)d_in[3];
    const float* wk  = (const float*)d_in[4];
    const float* wv  = (const float*)d_in[5];
    const float* wo  = (const float*)d_in[6];
    const float* wg  = (const float*)d_in[7];
    const float* wmg = (const float*)d_in[8];
    const float* w1  = (const float*)d_in[9];
    const float* w2  = (const float*)d_in[10];
    float* out = (float*)d_out;

    char* w = (char*)d_ws;
    const size_t MB = (size_t)1 << 20;
    // region A (66 MiB): QKVG fp32 [4096][4096] (64 MiB), later Hbig bf16 [8320][4096] (65 MiB)
    float* QKVG = (float*)(w + 0);
    u16*   Hbig = (u16*)(w + 0);
    u16*   h1b  = (u16*)(w + 66 * MB);   // 8 MiB: rms1 out -> attn out (bf16)
    u16*   h2b  = (u16*)(w + 74 * MB);   // 8 MiB
    float* h2f  = (float*)(w + 82 * MB); // 16 MiB
    u16*   wb4  = (u16*)(w + 98 * MB);   // 8 MiB: [wq;wk;wv;wg] bf16
    u16*   wob  = (u16*)(w + 106 * MB);  // 2 MiB
    u16*   w1b  = (u16*)(w + 108 * MB);  // 64 MiB
    u16*   w2b  = (u16*)(w + 172 * MB);  // 64 MiB
    float* logits = (float*)(w + 236 * MB);
    float* wgtl   = logits + (size_t)TDIM * EEXP;
    int*   idxl   = (int*)(wgtl + (size_t)TDIM * EEXP);
    int*   cnt    = idxl + (size_t)TDIM * EEXP;
    int*   offs   = cnt + EEXP;
    if (ws_size < 237 * MB) return;   // clean fail -> poisoned out flags the issue

    hipMemsetAsync(cnt, 0, 2 * EEXP * sizeof(int), stream);

    const int D2_4 = DDIM * DDIM / 4;
    cvt_kernel<<<1024, 256, 0, stream>>>(wq, wb4 + 0 * (size_t)DDIM * DDIM, D2_4);
    cvt_kernel<<<1024, 256, 0, stream>>>(wk, wb4 + 1 * (size_t)DDIM * DDIM, D2_4);
    cvt_kernel<<<1024, 256, 0, stream>>>(wv, wb4 + 2 * (size_t)DDIM * DDIM, D2_4);
    cvt_kernel<<<1024, 256, 0, stream>>>(wg, wb4 + 3 * (size_t)DDIM * DDIM, D2_4);
    cvt_kernel<<<1024, 256, 0, stream>>>(wo, wob, D2_4);
    cvt_kernel<<<2048, 256, 0, stream>>>(w1, w1b, EEXP * FDIM * DDIM / 4);
    cvt_kernel<<<2048, 256, 0, stream>>>(w2, w2b, EEXP * DDIM * FDIM / 4);

    rmsnorm_kernel<false><<<TDIM, 256, 0, stream>>>(x, n1w, h1b, nullptr);

    // QKVG fused projection: [4096,1024] x [4096,1024]^T -> [4096,4096]
    mgemm<EP_PLAIN, false><<<dim3(32, 32, 1), 256, 0, stream>>>(
        h1b, wb4, QKVG, nullptr, 4096, 1024, TDIM,
        nullptr, nullptr, nullptr, nullptr, nullptr, nullptr, 0);

    attn_kernel<<<dim3(32, 32), 256, 0, stream>>>(QKVG, h1b);

    // out = x + (attn @ wo^T) * sigmoid(gate_raw)
    mgemm<EP_RESID, false><<<dim3(8, 32, 1), 256, 0, stream>>>(
        h1b, wob, out, nullptr, 1024, 1024, TDIM,
        nullptr, nullptr, nullptr, nullptr, x, QKVG + 3072, 4096);

    rmsnorm_kernel<true><<<TDIM, 256, 0, stream>>>(out, n2w, h2b, h2f);
    moe_gate_kernel<<<TDIM / 32, 256, 0, stream>>>(h2f, wmg, logits);
    route_kernel<<<TDIM / 256, 256, 0, stream>>>(logits, cnt, idxl, wgtl);
    prefix_kernel<<<1, 64, 0, stream>>>(cnt, offs);

    // all experts, 2 launches (compact Hbig rows via offs)
    mgemm<EP_SILU, true><<<dim3(32, 32, 8), 256, 0, stream>>>(
        h2b, w1b, nullptr, Hbig, FDIM, DDIM, TDIM,
        cnt, offs, idxl, nullptr, nullptr, nullptr, 0);
    mgemm<EP_SCATTER, false><<<dim3(8, 32, 8), 256, 0, stream>>>(
        Hbig, w2b, out, nullptr, DDIM, FDIM, TDIM,
        cnt, offs, idxl, wgtl, nullptr, nullptr, 0);
}